// Round 9
// baseline (909.794 us; speedup 1.0000x reference)
//
#include <hip/hip_runtime.h>

#define R_ET 8
#define DH 128
#define KST 1152  // stacked K: 8 relation blocks (1024) + root block (128)
#define GW 1024   // G row width (8 relation blocks only; root read from Ain)

typedef __bf16 bf16x8 __attribute__((ext_vector_type(8)));
typedef float f32x4 __attribute__((ext_vector_type(4)));

__device__ __forceinline__ ushort f2bf(float f) {
  unsigned u = __float_as_uint(f);
  u += 0x7fff + ((u >> 16) & 1);  // round-to-nearest-even
  return (ushort)(u >> 16);
}

// Swizzled layouts (row r, stacked-k): pos = ((k>>3) ^ (r&7))*8 + (k&7). XOR is
// confined to the low 3 bits of the 16B-block index -> every 128-wide chunk is
// self-contained.
//
// Session lessons: r3 global-atomic contention ~ RMWs/line (~32/line free);
// r5/r7 LDS fp32 atomicAdd = CAS serialization (~900cy/edge) - NO fp atomics;
// r5 391-block fusion = TLP collapse; r8 unfused agg(66us)+gemm is the proven
// floor structure. r9: batch both graphs through preprocessing (one meta/off2
// space), gemm2 with A-dbuf async staging + B direct from L2-hot Wt.

// ---------------- degree count per (g, dst, etype) segment, both graphs ----------------
__global__ void count2_kernel(const int* __restrict__ ei0, const int* __restrict__ et0,
                              const int* __restrict__ ei1, const int* __restrict__ et1,
                              int* __restrict__ cnt, int E, int N) {
  int idx = blockIdx.x * blockDim.x + threadIdx.x;
  if (idx >= 2 * E) return;
  int g = idx >= E;
  int e = idx - (g ? E : 0);
  const int* ei = g ? ei1 : ei0;
  const int* et = g ? et1 : et0;
  atomicAdd(&cnt[(g * N + ei[E + e]) * R_ET + et[e]], 1);
}

// ---------------- 3-phase exclusive scan over M = 2*N*R segment counts ----------------
__global__ __launch_bounds__(1024) void scanA(const int* __restrict__ cnt,
                                              int* __restrict__ off,
                                              int* __restrict__ bsum, int M) {
  __shared__ int s[1024];
  int tid = threadIdx.x;
  int i = blockIdx.x * 1024 + tid;
  int d = (i < M) ? cnt[i] : 0;
  s[tid] = d;
  __syncthreads();
  for (int st = 1; st < 1024; st <<= 1) {
    int v = (tid >= st) ? s[tid - st] : 0;
    __syncthreads();
    s[tid] += v;
    __syncthreads();
  }
  if (i < M) off[i] = s[tid] - d;
  if (tid == 1023) bsum[blockIdx.x] = s[1023];
}

__global__ __launch_bounds__(1024) void scanB(int* __restrict__ bsum, int nb) {
  __shared__ int s[1024];
  int tid = threadIdx.x;
  int v = (tid < nb) ? bsum[tid] : 0;
  s[tid] = v;
  __syncthreads();
  for (int st = 1; st < 1024; st <<= 1) {
    int x = (tid >= st) ? s[tid - st] : 0;
    __syncthreads();
    s[tid] += x;
    __syncthreads();
  }
  if (tid < nb) bsum[tid] = s[tid] - v;
}

__global__ __launch_bounds__(1024) void scanC(int* __restrict__ off,
                                              int* __restrict__ cursor,
                                              const int* __restrict__ bsum,
                                              int M, int E2) {
  int i = blockIdx.x * 1024 + threadIdx.x;
  if (i < M) {
    int o = off[i] + bsum[blockIdx.x];
    off[i] = o;
    cursor[i] = o;
  }
  if (i == 0) off[M] = E2;
}

// ---------------- place edges into (g, dst, r)-sorted slots, both graphs ----------------
// meta: x = src (graph-local), y = 1/cnt. Proven contention profile (~32/line).
__global__ void place2_kernel(const int* __restrict__ ei0, const int* __restrict__ et0,
                              const int* __restrict__ ei1, const int* __restrict__ et1,
                              const int* __restrict__ cnt, int* __restrict__ cursor,
                              int2* __restrict__ meta, int E, int N) {
  int idx = blockIdx.x * blockDim.x + threadIdx.x;
  if (idx >= 2 * E) return;
  int g = idx >= E;
  int e = idx - (g ? E : 0);
  const int* ei = g ? ei1 : ei0;
  const int* et = g ? et1 : et0;
  int src = ei[e], dst = ei[E + e], r = et[e];
  int seg = (g * N + dst) * R_ET + r;
  int slot = atomicAdd(&cursor[seg], 1);
  meta[slot] = make_int2(src, __float_as_int(1.f / (float)cnt[seg]));
}

// ------- stacked weight convert (all 3 layers): Wt[l][n][k], swizzled ----------------
__global__ __launch_bounds__(256) void wconv_kernel(
    const float* __restrict__ r0, const float* __restrict__ w0,
    const float* __restrict__ r1, const float* __restrict__ w1,
    const float* __restrict__ r2, const float* __restrict__ w2,
    ushort* __restrict__ Wt) {
  int l = blockIdx.x / 9, mat = blockIdx.x % 9;  // mat 0..7 = W[r], 8 = root
  const float* root = (l == 0) ? r0 : (l == 1) ? r1 : r2;
  const float* W = (l == 0) ? w0 : (l == 1) ? w1 : w2;
  const float* src = (mat == 8) ? root : (W + (size_t)mat * DH * DH);
  ushort* dst = Wt + (size_t)l * DH * KST;
  for (int idx = threadIdx.x; idx < DH * DH; idx += 256) {
    int n = idx >> 7, kin = idx & 127;
    int k = mat * DH + kin;
    dst[(size_t)n * KST + (((k >> 3) ^ (n & 7)) << 3) + (k & 7)] = f2bf(src[kin * DH + n]);
  }
}

// ---------------- activation convert (layer 0), zero-pads rows, swizzled ----------------
__global__ __launch_bounds__(256) void aconv_kernel(const float* __restrict__ src,
                                                    ushort* __restrict__ dst,
                                                    int total, int padtotal) {
  int i4 = (blockIdx.x * 256 + threadIdx.x) * 4;
  if (i4 >= padtotal) return;
  int row = i4 >> 7, k = i4 & 127;
  ushort4 o = make_ushort4(0, 0, 0, 0);
  if (i4 < total) {
    float4 v = *(const float4*)&src[i4];
    o = make_ushort4(f2bf(v.x), f2bf(v.y), f2bf(v.z), f2bf(v.w));
  }
  *(ushort4*)&dst[(size_t)row * DH + (((k >> 3) ^ (row & 7)) << 3) + (k & 7)] = o;
}

// ============ aggregation: 1 wave per dst (r8-proven, unchanged) ==================
// off2 pointer is pre-offset by g*N*R_ET at launch; meta slots are global.
__global__ __launch_bounds__(256) void agg_kernel(
    const int* __restrict__ off2, const int2* __restrict__ meta,
    const ushort* __restrict__ Ain, ushort* __restrict__ G, int N, int Npad) {
  int dst = blockIdx.x * 4 + (threadIdx.x >> 6);
  if (dst >= Npad) return;
  int lane = threadIdx.x & 63;
  const int kb = lane >> 2;             // (k>>3) for k = 2*lane
  const int klo = (lane * 2) & 7;       // (k&7)
  const int swz = dst & 7;

  int offv = 0;
  if (dst < N && lane < 9) offv = off2[dst * R_ET + lane];
  const int s_all = __shfl(offv, 0);
  const int e_end = __shfl(offv, 8);

  float ax[R_ET], ay[R_ET];
#pragma unroll
  for (int r = 0; r < R_ET; r++) { ax[r] = 0.f; ay[r] = 0.f; }

  for (int base = s_all; base < e_end; base += 64) {
    int m = min(64, e_end - base);
    int2 md = make_int2(0, 0);
    if (lane < m) md = meta[base + lane];
#pragma unroll
    for (int r = 0; r < R_ET; r++) {
      int s0 = max(__shfl(offv, r), base);
      int s1 = min(__shfl(offv, r + 1), base + m);
      for (int e = s0; e < s1; e++) {
        int p = __shfl(md.x, e - base);
        float c = __int_as_float(__shfl(md.y, e - base));
        unsigned v = *(const unsigned*)&Ain[((size_t)p << 7) + ((kb ^ (p & 7)) << 3) + klo];
        ax[r] = fmaf(__uint_as_float(v << 16), c, ax[r]);
        ay[r] = fmaf(__uint_as_float(v & 0xffff0000u), c, ay[r]);
      }
    }
  }

  ushort* Grow = G + (size_t)dst * GW;
#pragma unroll
  for (int r = 0; r < R_ET; r++) {
    unsigned o = (unsigned)f2bf(ax[r]) | ((unsigned)f2bf(ay[r]) << 16);
    *(unsigned*)&Grow[(((r * 16 + kb) ^ swz) << 3) + klo] = o;
  }
}

// ============ K=1152 MFMA GEMM v2: A double-buffered async, B from L2-hot Wt ========
// grid Npad/128; 256 thr (4 waves, 64x64 quadrants). Per chunk kc: issue async
// global_load_lds staging of chunk kc+1 into the other LDS buffer, then MFMA over
// the current buffer with B fragments read straight from Wt (32KB chunk shared by
// all blocks -> L2-hot; 16 full lines per fragment instruction). One barrier per
// chunk (9 vs 18 in r8); staging latency hides under MFMA + B-loads.
__global__ __launch_bounds__(256) void gemm2(
    const ushort* __restrict__ G, const ushort* __restrict__ Ain,
    const ushort* __restrict__ Wt, const float* __restrict__ bias,
    ushort* __restrict__ Aout, float* __restrict__ pbuf, int N, int last) {
  __shared__ ushort As[2][128 * DH];  // 2 x 32 KB
  __shared__ float sb[2][DH];
  const int tid = threadIdx.x;
  const int wave = tid >> 6, lane = tid & 63;
  const int quad = lane >> 4, l15 = lane & 15;
  const int rbase = blockIdx.x * 128;
  const int wr = (wave >> 1) * 64, wc = (wave & 1) * 64;

  auto stage = [&](int kc, int buf) {
#pragma unroll
    for (int it = 0; it < 8; it++) {
      int i = it * 256 + tid;
      int row = i >> 4, b = i & 15;
      const ushort* srcA = (kc < 8)
          ? G + (size_t)(rbase + row) * GW + kc * 128 + b * 8
          : Ain + (size_t)(rbase + row) * DH + b * 8;
      __builtin_amdgcn_global_load_lds(
          (const __attribute__((address_space(1))) void*)srcA,
          (__attribute__((address_space(3))) void*)(&As[buf][(it * 256 + wave * 64) * 8]),
          16, 0, 0);
    }
  };

  f32x4 acc[4][4];
#pragma unroll
  for (int i = 0; i < 4; i++)
#pragma unroll
    for (int j = 0; j < 4; j++) acc[i][j] = (f32x4){0.f, 0.f, 0.f, 0.f};

  stage(0, 0);
  __syncthreads();
  for (int kc = 0; kc < 9; kc++) {
    const int buf = kc & 1;
    if (kc < 8) stage(kc + 1, buf ^ 1);
#pragma unroll
    for (int ks = 0; ks < 4; ks++) {
      const int b8 = kc * 16 + ks * 4 + quad;  // stacked 16B-block index
      bf16x8 af[4], bfr[4];
#pragma unroll
      for (int i = 0; i < 4; i++) {
        int ra = wr + i * 16 + l15;
        int rb = wc + i * 16 + l15;
        af[i] = *(const bf16x8*)&As[buf][ra * DH + (((ks * 4 + quad) ^ (ra & 7)) << 3)];
        bfr[i] = *(const bf16x8*)&Wt[(size_t)rb * KST + ((b8 ^ (rb & 7)) << 3)];
      }
#pragma unroll
      for (int i = 0; i < 4; i++)
#pragma unroll
        for (int j = 0; j < 4; j++)
          acc[i][j] = __builtin_amdgcn_mfma_f32_16x16x32_bf16(bfr[j], af[i], acc[i][j], 0, 0, 0);
    }
    __syncthreads();  // all reads of As[buf] done; staged chunk kc+1 drained
  }

  // ---- epilogue (r8-proven) ----
  if (!last) {
#pragma unroll
    for (int i = 0; i < 4; i++) {
      int node = rbase + wr + i * 16 + l15;
      bool ok = node < N;
#pragma unroll
      for (int j = 0; j < 4; j++) {
        int c0 = wc + j * 16 + quad * 4;
        float4 bv = *(const float4*)&bias[c0];
        unsigned lo = 0, hi = 0;
        if (ok) {
          lo = (unsigned)f2bf(fmaxf(acc[i][j][0] + bv.x, 0.f)) |
               ((unsigned)f2bf(fmaxf(acc[i][j][1] + bv.y, 0.f)) << 16);
          hi = (unsigned)f2bf(fmaxf(acc[i][j][2] + bv.z, 0.f)) |
               ((unsigned)f2bf(fmaxf(acc[i][j][3] + bv.w, 0.f)) << 16);
        }
        *(uint2*)&Aout[(size_t)node * DH + (((c0 >> 3) ^ (node & 7)) << 3) + (c0 & 7)] =
            make_uint2(lo, hi);  // pad rows get zeros
      }
    }
  } else {
    // column partials; pad rows are exact zeros (no bias here)
    if (tid < 2 * DH) ((float*)sb)[tid] = 0.f;
    __syncthreads();
    const int half = wave >> 1;
#pragma unroll
    for (int j = 0; j < 4; j++) {
      f32x4 s;
#pragma unroll
      for (int c = 0; c < 4; c++)
        s[c] = acc[0][j][c] + acc[1][j][c] + acc[2][j][c] + acc[3][j][c];
#pragma unroll
      for (int mask = 1; mask < 16; mask <<= 1)
#pragma unroll
        for (int c = 0; c < 4; c++) s[c] += __shfl_xor(s[c], mask);
      if (l15 == 0) {
        int c0 = wc + j * 16 + quad * 4;
#pragma unroll
        for (int c = 0; c < 4; c++) sb[half][c0 + c] = s[c];
      }
    }
    __syncthreads();
    if (tid < DH) pbuf[(size_t)blockIdx.x * DH + tid] = sb[0][tid] + sb[1][tid];
  }
}

// ---------------- reduce per-block partials -> u ----------------
__global__ __launch_bounds__(256) void pool_reduce(const float* __restrict__ pbuf,
                                                   float* __restrict__ u, int nblk) {
  __shared__ float s[256];
  int tid = threadIdx.x;
  int c = tid & 127, h = tid >> 7;
  int chunk = (nblk + gridDim.x - 1) / gridDim.x;
  int r0 = blockIdx.x * chunk;
  int r1 = min(r0 + chunk, nblk);
  float sum = 0.f;
  for (int r = r0 + h; r < r1; r += 2) sum += pbuf[(size_t)r * 128 + c];
  s[tid] = sum;
  __syncthreads();
  if (tid < 128) atomicAdd(&u[c], s[tid] + s[tid + 128]);
}

// ---------------- final MLP on concat(u1/N + b2, u2/N + b2) ----------------
__global__ __launch_bounds__(256) void mlp_kernel(
    const float* __restrict__ u, const float* __restrict__ b2,
    const float* __restrict__ fc1w, const float* __restrict__ fc1b,
    const float* __restrict__ fc2w, const float* __restrict__ fc2b,
    float* __restrict__ out, int N) {
  __shared__ float uin[256];
  __shared__ float hred[128];
  int tid = threadIdx.x;
  uin[tid] = u[tid] * (1.f / (float)N) + b2[tid & 127];
  __syncthreads();
  if (tid < 128) {
    float s = fc1b[tid];
    for (int i = 0; i < 256; i++) s = fmaf(uin[i], fc1w[i * 128 + tid], s);
    s = fmaxf(s, 0.f);
    hred[tid] = s * fc2w[tid];
  }
  __syncthreads();
  if (tid == 0) {
    float s = fc2b[0];
    for (int i = 0; i < 128; i++) s += hred[i];
    out[0] = s;
  }
}

extern "C" void kernel_launch(void* const* d_in, const int* in_sizes, int n_in,
                              void* d_out, int out_size, void* d_ws, size_t ws_size,
                              hipStream_t stream) {
  const float* x[2] = {(const float*)d_in[0], (const float*)d_in[3]};
  const int* ei[2] = {(const int*)d_in[1], (const int*)d_in[4]};
  const int* et[2] = {(const int*)d_in[2], (const int*)d_in[5]};
  const float* Wp[3] = {(const float*)d_in[6], (const float*)d_in[9], (const float*)d_in[12]};
  const float* rootp[3] = {(const float*)d_in[7], (const float*)d_in[10], (const float*)d_in[13]};
  const float* biasp[3] = {(const float*)d_in[8], (const float*)d_in[11], (const float*)d_in[14]};
  const float* fc1w = (const float*)d_in[15];
  const float* fc1b = (const float*)d_in[16];
  const float* fc2w = (const float*)d_in[17];
  const float* fc2b = (const float*)d_in[18];

  const int N = in_sizes[0] / DH;
  const int E = in_sizes[2];
  const int Npad = (N + 127) & ~127;
  const int ngB = Npad / 128;             // gemm2 blocks per graph
  const int M2 = 2 * N * R_ET;            // (g, dst, r) segments, both graphs
  const int MB2 = (M2 + 1023) / 1024;     // scan blocks (<=1024)

  char* ws = (char*)d_ws;
  size_t ob = 0;
  auto alloc = [&](size_t bytes) {
    void* p = ws + ob;
    ob = (ob + bytes + 255) & ~(size_t)255;
    return p;
  };
  int* cnt2 = (int*)alloc((size_t)M2 * 4);
  int* off2 = (int*)alloc((size_t)(M2 + 1) * 4);
  int* cursor2 = (int*)alloc((size_t)M2 * 4);
  int* bsum = (int*)alloc(1024 * 4);
  int2* meta = (int2*)alloc((size_t)2 * E * 8);
  float* u = (float*)alloc(1024);
  float* pbuf = (float*)alloc((size_t)ngB * DH * 4);
  ushort* A0 = (ushort*)alloc((size_t)Npad * DH * 2);
  ushort* B1 = (ushort*)alloc((size_t)Npad * DH * 2);
  ushort* B2 = (ushort*)alloc((size_t)Npad * DH * 2);
  ushort* G = (ushort*)alloc((size_t)Npad * GW * 2);
  ushort* Wt = (ushort*)alloc((size_t)3 * DH * KST * 2);
  (void)ws_size;

  hipMemsetAsync(u, 0, 2 * DH * sizeof(float), stream);
  hipMemsetAsync(cnt2, 0, (size_t)M2 * sizeof(int), stream);
  wconv_kernel<<<27, 256, 0, stream>>>(rootp[0], Wp[0], rootp[1], Wp[1],
                                       rootp[2], Wp[2], Wt);

  dim3 e2grid((2 * E + 255) / 256);
  dim3 nagrid((Npad + 3) / 4);
  const int total = N * DH, padtotal = Npad * DH;
  dim3 agrid((padtotal / 4 + 255) / 256);

  // batched preprocessing for both graphs
  count2_kernel<<<e2grid, 256, 0, stream>>>(ei[0], et[0], ei[1], et[1], cnt2, E, N);
  scanA<<<MB2, 1024, 0, stream>>>(cnt2, off2, bsum, M2);
  scanB<<<1, 1024, 0, stream>>>(bsum, MB2);
  scanC<<<MB2, 1024, 0, stream>>>(off2, cursor2, bsum, M2, 2 * E);
  place2_kernel<<<e2grid, 256, 0, stream>>>(ei[0], et[0], ei[1], et[1], cnt2,
                                            cursor2, meta, E, N);

  for (int g = 0; g < 2; g++) {
    const int* offg = off2 + (size_t)g * N * R_ET;
    aconv_kernel<<<agrid, 256, 0, stream>>>(x[g], A0, total, padtotal);

    agg_kernel<<<nagrid, 256, 0, stream>>>(offg, meta, A0, G, N, Npad);
    gemm2<<<ngB, 256, 0, stream>>>(G, A0, Wt, biasp[0], B1, nullptr, N, 0);
    agg_kernel<<<nagrid, 256, 0, stream>>>(offg, meta, B1, G, N, Npad);
    gemm2<<<ngB, 256, 0, stream>>>(G, B1, Wt + (size_t)DH * KST, biasp[1], B2, nullptr, N, 0);
    agg_kernel<<<nagrid, 256, 0, stream>>>(offg, meta, B2, G, N, Npad);
    gemm2<<<ngB, 256, 0, stream>>>(G, B2, Wt + (size_t)2 * DH * KST, nullptr, nullptr, pbuf, N, 1);
    pool_reduce<<<100, 256, 0, stream>>>(pbuf, u + g * DH, ngB);
  }
  mlp_kernel<<<1, 256, 0, stream>>>(u, biasp[2], fc1w, fc1b, fc2w, fc2b,
                                    (float*)d_out, N);
}